// Round 4
// baseline (1326.103 us; speedup 1.0000x reference)
//
#include <hip/hip_runtime.h>

// ShootingBlock: only the u-trajectory is observable (traj records y[2K:];
// du = relu(u)@theta^T + bias is self-contained; Mbar/Mbar_b are identity).
//
// R4: feval is a no-LDS, no-barrier fp32 GEMM. R3 was LDS-instruction-bound
// (8192 ds_read_b128 x 12cyc = 98k cyc/CU/feval vs 32.8k cyc of FMA issue ->
// VALUBusy 33%). Now A (yin^T, 256B segments) and B (thetaT, 1MB, L2-hot)
// stream via global_load_dwordx4 on the TA/L1/L2 path, parallel to VALU.
// 4x8 microtile, depth-4 software pipeline, 128 thr, grid (64,8)=512
// (2 blocks/CU = 4 waves on 4 SIMDs). VALU floor: 32768 cyc/CU = 13.7 us.

namespace {

constexpr int KP = 1024;
constexpr int D  = 512;
constexpr int M  = 4096;

// ---------------------------------------------------------------------------
// part[z][e][d] = sum_{k in chunk z} relu(xs[k][e]) * ps[k][d]   (thetaT order)
// ---------------------------------------------------------------------------
constexpr int TBK = 32;
constexpr int TLD = 68;
constexpr int KSPLIT = 8;

__global__ __launch_bounds__(256) void theta_partial_kernel(
    const float* __restrict__ xs, const float* __restrict__ ps,
    float* __restrict__ part) {
  __shared__ float As[TBK][TLD];  // relu(xs), e-block
  __shared__ float Bs[TBK][TLD];  // ps, d-block
  const int e0 = blockIdx.x * 64;
  const int d0 = blockIdx.y * 64;
  const int kb = blockIdx.z * (KP / KSPLIT);
  const int t  = threadIdx.x;
  const int tx = t & 15, ty = t >> 4;
  float acc[4][4] = {};

  for (int k0 = kb; k0 < kb + KP / KSPLIT; k0 += TBK) {
#pragma unroll
    for (int p = 0; p < 2; ++p) {
      const int idx = t + p * 256;
      const int c4  = idx & 15;
      const int row = idx >> 4;
      float4 av = *(const float4*)(xs + (size_t)(k0 + row) * D + e0 + c4 * 4);
      av.x = fmaxf(av.x, 0.f); av.y = fmaxf(av.y, 0.f);
      av.z = fmaxf(av.z, 0.f); av.w = fmaxf(av.w, 0.f);
      *(float4*)&As[row][c4 * 4] = av;
      const float4 bv = *(const float4*)(ps + (size_t)(k0 + row) * D + d0 + c4 * 4);
      *(float4*)&Bs[row][c4 * 4] = bv;
    }
    __syncthreads();
#pragma unroll
    for (int kk = 0; kk < TBK; ++kk) {
      const float4 a4 = *(const float4*)&As[kk][ty * 4];
      const float4 b4 = *(const float4*)&Bs[kk][tx * 4];
      const float a[4] = {a4.x, a4.y, a4.z, a4.w};
      const float b[4] = {b4.x, b4.y, b4.z, b4.w};
#pragma unroll
      for (int i = 0; i < 4; ++i)
#pragma unroll
        for (int j = 0; j < 4; ++j)
          acc[i][j] = fmaf(a[i], b[j], acc[i][j]);
    }
    __syncthreads();
  }
  float* dst = part + (size_t)blockIdx.z * D * D;
#pragma unroll
  for (int i = 0; i < 4; ++i) {
    float4 v;
    v.x = acc[i][0]; v.y = acc[i][1]; v.z = acc[i][2]; v.w = acc[i][3];
    *(float4*)(dst + (size_t)(e0 + ty * 4 + i) * D + d0 + tx * 4) = v;
  }
}

__global__ __launch_bounds__(256) void theta_combine_kernel(
    const float* __restrict__ part, float* __restrict__ thetaT) {
  const size_t i = (size_t)blockIdx.x * 256 + threadIdx.x;  // float4 index
  float4 s = ((const float4*)part)[i];
#pragma unroll
  for (int z = 1; z < KSPLIT; ++z) {
    const float4 v = ((const float4*)(part + (size_t)z * D * D))[i];
    s.x += v.x; s.y += v.y; s.z += v.z; s.w += v.w;
  }
  s.x = -s.x; s.y = -s.y; s.z = -s.z; s.w = -s.w;
  ((float4*)thetaT)[i] = s;
}

__global__ __launch_bounds__(256) void bias_kernel(const float* __restrict__ ps,
                                                   float* __restrict__ bias) {
  __shared__ float part[4][64];
  const int dc = threadIdx.x & 63;
  const int sl = threadIdx.x >> 6;
  const int d  = blockIdx.x * 64 + dc;
  float s = 0.f;
  for (int k = sl * 256; k < sl * 256 + 256; ++k) s += ps[(size_t)k * D + d];
  part[sl][dc] = s;
  __syncthreads();
  if (threadIdx.x < 64) {
    const int c = threadIdx.x;
    bias[blockIdx.x * 64 + c] =
        -(part[0][c] + part[1][c] + part[2][c] + part[3][c]);
  }
}

// ---------------------------------------------------------------------------
// out0 = inp (copy); yin = relu(inp)^T.  64x64 tiles through LDS.
// ---------------------------------------------------------------------------
__global__ __launch_bounds__(256) void init_kernel(const float* __restrict__ inp,
                                                   float* __restrict__ out0,
                                                   float* __restrict__ yin) {
  __shared__ float Tr[64][68];
  const int t  = threadIdx.x;
  const int m0 = blockIdx.x * 64, e0 = blockIdx.y * 64;
  const int cc = t & 15;
#pragma unroll
  for (int p = 0; p < 4; ++p) {
    const int row = (t >> 4) + p * 16;  // m row
    const size_t g = (size_t)(m0 + row) * D + e0 + cc * 4;
    const float4 v = *(const float4*)(inp + g);
    *(float4*)(out0 + g) = v;
    Tr[cc * 4 + 0][row] = v.x;
    Tr[cc * 4 + 1][row] = v.y;
    Tr[cc * 4 + 2][row] = v.z;
    Tr[cc * 4 + 3][row] = v.w;
  }
  __syncthreads();
#pragma unroll
  for (int p = 0; p < 4; ++p) {
    const int row = (t >> 4) + p * 16;  // e row
    const float4 v = *(const float4*)&Tr[row][cc * 4];
    float4 y;
    y.x = fmaxf(v.x, 0.f); y.y = fmaxf(v.y, 0.f);
    y.z = fmaxf(v.z, 0.f); y.w = fmaxf(v.w, 0.f);
    *(float4*)(yin + (size_t)(e0 + row) * M + m0 + cc * 4) = y;
  }
}

// ---------------------------------------------------------------------------
// feval<MODE>: k[m][n] = bias[n] + sum_e yinRd[e][m] * thetaT[e][n]
//  MODE 0: acc = k;           yinWr = relu(u + dt/2 k)^T
//  MODE 1: acc += 2k;         yinWr = relu(u + dt/2 k)^T
//  MODE 2: acc += 2k;         yinWr = relu(u + dt   k)^T
//  MODE 3: unew = u + dt/6 (acc + k) -> outStd;  yinWr = relu(unew)^T
// No LDS, no barriers. 4x8 microtile: per e, 3 coalesced dwordx4 loads + 32
// FMAs, software-pipelined depth 4. n-extent = two float4s 32 apart so every
// load/store instruction covers a contiguous 128-256B segment per lane group.
// ---------------------------------------------------------------------------
template <int MODE>
__global__ __launch_bounds__(128) void feval_kernel(
    const float* __restrict__ yinRd, const float* __restrict__ thetaT,
    const float* __restrict__ bias, const float* __restrict__ bt, int step,
    const float* __restrict__ uStd, float* __restrict__ acc,
    float* __restrict__ yinWr, float* __restrict__ outStd) {
  const int t  = threadIdx.x;
  const int tx = t & 7;        // n-group (8)
  const int ty = t >> 3;       // m-group (16)
  const int m0 = blockIdx.x * 64 + ty * 4;
  const int n0 = blockIdx.y * 64;
  const int nA = n0 + tx * 4;
  const int nB = n0 + 32 + tx * 4;
  const float dt = bt[step + 1] - bt[step];

  float accr[4][8] = {};  // [i][j]: j<4 -> nA+j, j>=4 -> nB+(j-4)

  constexpr int PF = 4;
  float4 ab[PF], b0b[PF], b1b[PF];
  const float* aP  = yinRd + m0;
  const float* bP0 = thetaT + nA;
  const float* bP1 = thetaT + nB;
#pragma unroll
  for (int p = 0; p < PF; ++p) {
    ab[p]  = *(const float4*)(aP + (size_t)p * M);
    b0b[p] = *(const float4*)(bP0 + (size_t)p * D);
    b1b[p] = *(const float4*)(bP1 + (size_t)p * D);
  }

  for (int e = 0; e + PF < D; e += PF) {
#pragma unroll
    for (int p = 0; p < PF; ++p) {
      const float4 a4 = ab[p];
      const float4 b0 = b0b[p];
      const float4 b1 = b1b[p];
      const int en = e + PF + p;  // prefetch
      ab[p]  = *(const float4*)(aP + (size_t)en * M);
      b0b[p] = *(const float4*)(bP0 + (size_t)en * D);
      b1b[p] = *(const float4*)(bP1 + (size_t)en * D);
      const float a[4] = {a4.x, a4.y, a4.z, a4.w};
      const float b[8] = {b0.x, b0.y, b0.z, b0.w, b1.x, b1.y, b1.z, b1.w};
#pragma unroll
      for (int i = 0; i < 4; ++i)
#pragma unroll
        for (int j = 0; j < 8; ++j)
          accr[i][j] = fmaf(a[i], b[j], accr[i][j]);
    }
  }
#pragma unroll
  for (int p = 0; p < PF; ++p) {  // tail group e = D-PF..D-1
    const float4 a4 = ab[p];
    const float4 b0 = b0b[p];
    const float4 b1 = b1b[p];
    const float a[4] = {a4.x, a4.y, a4.z, a4.w};
    const float b[8] = {b0.x, b0.y, b0.z, b0.w, b1.x, b1.y, b1.z, b1.w};
#pragma unroll
    for (int i = 0; i < 4; ++i)
#pragma unroll
      for (int j = 0; j < 8; ++j)
        accr[i][j] = fmaf(a[i], b[j], accr[i][j]);
  }

  // ---- epilogue -------------------------------------------------------------
  const float4 bvA = *(const float4*)(bias + nA);
  const float4 bvB = *(const float4*)(bias + nB);
  const float bb[8] = {bvA.x, bvA.y, bvA.z, bvA.w, bvB.x, bvB.y, bvB.z, bvB.w};
  float k[4][8];
#pragma unroll
  for (int i = 0; i < 4; ++i)
#pragma unroll
    for (int j = 0; j < 8; ++j) k[i][j] = accr[i][j] + bb[j];

  float y[4][8];  // value whose relu^T goes to yinWr
  if constexpr (MODE <= 2) {
    const float cn = (MODE == 2) ? dt : 0.5f * dt;
#pragma unroll
    for (int i = 0; i < 4; ++i) {
      const size_t offA = (size_t)(m0 + i) * D + nA;
      const size_t offB = (size_t)(m0 + i) * D + nB;
      float4 kA, kB;
      kA.x = k[i][0]; kA.y = k[i][1]; kA.z = k[i][2]; kA.w = k[i][3];
      kB.x = k[i][4]; kB.y = k[i][5]; kB.z = k[i][6]; kB.w = k[i][7];
      if constexpr (MODE == 0) {
        *(float4*)(acc + offA) = kA;
        *(float4*)(acc + offB) = kB;
      } else {
        float4 aA = *(const float4*)(acc + offA);
        float4 aB = *(const float4*)(acc + offB);
        aA.x = fmaf(2.f, kA.x, aA.x); aA.y = fmaf(2.f, kA.y, aA.y);
        aA.z = fmaf(2.f, kA.z, aA.z); aA.w = fmaf(2.f, kA.w, aA.w);
        aB.x = fmaf(2.f, kB.x, aB.x); aB.y = fmaf(2.f, kB.y, aB.y);
        aB.z = fmaf(2.f, kB.z, aB.z); aB.w = fmaf(2.f, kB.w, aB.w);
        *(float4*)(acc + offA) = aA;
        *(float4*)(acc + offB) = aB;
      }
      const float4 uA = *(const float4*)(uStd + offA);
      const float4 uB = *(const float4*)(uStd + offB);
      const float uu[8] = {uA.x, uA.y, uA.z, uA.w, uB.x, uB.y, uB.z, uB.w};
#pragma unroll
      for (int j = 0; j < 8; ++j) y[i][j] = fmaf(cn, k[i][j], uu[j]);
    }
  } else {
    const float s6 = dt * (1.f / 6.f);
#pragma unroll
    for (int i = 0; i < 4; ++i) {
      const size_t offA = (size_t)(m0 + i) * D + nA;
      const size_t offB = (size_t)(m0 + i) * D + nB;
      const float4 uA = *(const float4*)(uStd + offA);
      const float4 uB = *(const float4*)(uStd + offB);
      const float4 aA = *(const float4*)(acc + offA);
      const float4 aB = *(const float4*)(acc + offB);
      float4 oA, oB;
      oA.x = fmaf(s6, aA.x + k[i][0], uA.x);
      oA.y = fmaf(s6, aA.y + k[i][1], uA.y);
      oA.z = fmaf(s6, aA.z + k[i][2], uA.z);
      oA.w = fmaf(s6, aA.w + k[i][3], uA.w);
      oB.x = fmaf(s6, aB.x + k[i][4], uB.x);
      oB.y = fmaf(s6, aB.y + k[i][5], uB.y);
      oB.z = fmaf(s6, aB.z + k[i][6], uB.z);
      oB.w = fmaf(s6, aB.w + k[i][7], uB.w);
      *(float4*)(outStd + offA) = oA;
      *(float4*)(outStd + offB) = oB;
      y[i][0] = oA.x; y[i][1] = oA.y; y[i][2] = oA.z; y[i][3] = oA.w;
      y[i][4] = oB.x; y[i][5] = oB.y; y[i][6] = oB.z; y[i][7] = oB.w;
    }
  }
  // yinWr[e][m] = relu(y)^T: column float4 per j, 128-256B segments per instr
#pragma unroll
  for (int j = 0; j < 8; ++j) {
    const int e = (j < 4) ? (nA + j) : (nB + j - 4);
    float4 v;
    v.x = fmaxf(y[0][j], 0.f);
    v.y = fmaxf(y[1][j], 0.f);
    v.z = fmaxf(y[2][j], 0.f);
    v.w = fmaxf(y[3][j], 0.f);
    *(float4*)(yinWr + (size_t)e * M + m0) = v;
  }
}

}  // namespace

extern "C" void kernel_launch(void* const* d_in, const int* in_sizes, int n_in,
                              void* d_out, int out_size, void* d_ws, size_t ws_size,
                              hipStream_t stream) {
  (void)in_sizes; (void)n_in; (void)out_size; (void)ws_size;
  const float* xs  = (const float*)d_in[0];  // x_params (K,1,D)
  const float* ps  = (const float*)d_in[1];  // p_params (K,1,D)
  // d_in[2] Mbar, d_in[3] Mbar_b: identity -> inv() no-op
  const float* inp = (const float*)d_in[4];  // (M,1,D)
  const float* bt  = (const float*)d_in[5];  // (T,)
  float* out = (float*)d_out;                // (T, M, 1, D)
  float* ws  = (float*)d_ws;

  float* thetaT = ws;                           // D*D floats (1 MB), [e][d]
  float* bias   = thetaT + (size_t)D * D;       // 512
  float* yinA   = bias + 512;                   // D*M (8 MB), [e][m]
  float* yinB   = yinA + (size_t)D * M;         // D*M
  float* acc    = yinB + (size_t)D * M;         // M*D   (total ~25.2 MB)
  float* part   = acc;  // theta partials (8*D*D = M*D floats) alias acc

  theta_partial_kernel<<<dim3(8, 8, KSPLIT), 256, 0, stream>>>(xs, ps, part);
  theta_combine_kernel<<<(D * D) / (4 * 256), 256, 0, stream>>>(part, thetaT);
  bias_kernel<<<D / 64, 256, 0, stream>>>(ps, bias);
  init_kernel<<<dim3(M / 64, D / 64), 256, 0, stream>>>(inp, out, yinA);

  const dim3 grid(M / 64, D / 64);  // (64, 8) = 512 blocks
  for (int s = 0; s < 5; ++s) {
    float* u     = out + (size_t)s * M * D;
    float* unext = out + (size_t)(s + 1) * M * D;
    feval_kernel<0><<<grid, 128, 0, stream>>>(yinA, thetaT, bias, bt, s, u, acc, yinB, nullptr);
    feval_kernel<1><<<grid, 128, 0, stream>>>(yinB, thetaT, bias, bt, s, u, acc, yinA, nullptr);
    feval_kernel<2><<<grid, 128, 0, stream>>>(yinA, thetaT, bias, bt, s, u, acc, yinB, nullptr);
    feval_kernel<3><<<grid, 128, 0, stream>>>(yinB, thetaT, bias, bt, s, u, acc, yinA, unext);
  }
}

// Round 5
// 778.806 us; speedup vs baseline: 1.7027x; 1.7027x over previous
//
#include <hip/hip_runtime.h>

// ShootingBlock: only the u-trajectory is observable (traj records y[2K:];
// du = relu(u)@theta^T + bias is self-contained; Mbar/Mbar_b are identity).
//
// R5: feval GEMM moves to the MFMA pipe via split-3 bf16:
//   a = a0+a1+a2 (bf16 RNE splits, residual ~2^-24), product = 6 MFMAs
//   (00,01,10,02,11,20) accumulated in fp32 -> ~2x fp32 eps per product.
// theta split once; each epilogue emits the next stage's relu'd split-3 A.
// MFMA-natural layouts (A=[m][k], B=theta[n][k], C/D=[m][n]) eliminate all
// transposes. Staging = pure global_load_lds DMA, double-buffered.
// Per-CU per-feval: matrix pipe 14.9k cyc, LDS pipe 13.8k cyc, overlapped.

namespace {

constexpr int KP = 1024;
constexpr int D  = 512;
constexpr int M  = 4096;

typedef __attribute__((ext_vector_type(8))) short short8;   // 8 bf16 (4 VGPRs)
typedef __attribute__((ext_vector_type(4))) float f32x4;

__device__ __forceinline__ unsigned short f2bf(float f) {  // RNE
  unsigned int u = __float_as_uint(f);
  u += 0x7FFF + ((u >> 16) & 1);
  return (unsigned short)(u >> 16);
}
__device__ __forceinline__ float bf2f(unsigned short h) {
  return __uint_as_float(((unsigned int)h) << 16);
}

__device__ __forceinline__ void glds16(const unsigned short* g, unsigned short* l) {
  __builtin_amdgcn_global_load_lds(
      (__attribute__((address_space(1))) const void*)g,
      (__attribute__((address_space(3))) void*)l, 16, 0, 0);
}

// ---------------------------------------------------------------------------
// part[z][d][e] = sum_{k in chunk z} ps[k][d] * relu(xs[k][e])   (std layout)
// ---------------------------------------------------------------------------
constexpr int KSPLIT = 8;

__global__ __launch_bounds__(256) void theta_partial_kernel(
    const float* __restrict__ xs, const float* __restrict__ ps,
    float* __restrict__ part) {
  __shared__ float As[32][68];  // ps, d-block
  __shared__ float Bs[32][68];  // relu(xs), e-block
  const int d0 = blockIdx.x * 64;
  const int e0 = blockIdx.y * 64;
  const int kb = blockIdx.z * (KP / KSPLIT);
  const int t  = threadIdx.x;
  const int tx = t & 15, ty = t >> 4;
  float acc[4][4] = {};

  for (int k0 = kb; k0 < kb + KP / KSPLIT; k0 += 32) {
#pragma unroll
    for (int p = 0; p < 2; ++p) {
      const int idx = t + p * 256;
      const int c4  = idx & 15;
      const int row = idx >> 4;
      const float4 av = *(const float4*)(ps + (size_t)(k0 + row) * D + d0 + c4 * 4);
      *(float4*)&As[row][c4 * 4] = av;
      float4 bv = *(const float4*)(xs + (size_t)(k0 + row) * D + e0 + c4 * 4);
      bv.x = fmaxf(bv.x, 0.f); bv.y = fmaxf(bv.y, 0.f);
      bv.z = fmaxf(bv.z, 0.f); bv.w = fmaxf(bv.w, 0.f);
      *(float4*)&Bs[row][c4 * 4] = bv;
    }
    __syncthreads();
#pragma unroll
    for (int kk = 0; kk < 32; ++kk) {
      const float4 a4 = *(const float4*)&As[kk][ty * 4];
      const float4 b4 = *(const float4*)&Bs[kk][tx * 4];
      const float a[4] = {a4.x, a4.y, a4.z, a4.w};
      const float b[4] = {b4.x, b4.y, b4.z, b4.w};
#pragma unroll
      for (int i = 0; i < 4; ++i)
#pragma unroll
        for (int j = 0; j < 4; ++j)
          acc[i][j] = fmaf(a[i], b[j], acc[i][j]);
    }
    __syncthreads();
  }
  float* dst = part + (size_t)blockIdx.z * D * D;
#pragma unroll
  for (int i = 0; i < 4; ++i) {
    float4 v;
    v.x = acc[i][0]; v.y = acc[i][1]; v.z = acc[i][2]; v.w = acc[i][3];
    *(float4*)(dst + (size_t)(d0 + ty * 4 + i) * D + e0 + tx * 4) = v;
  }
}

// theta = -(sum partials); split-3 into bf16 arrays th0,th1,th2 [d][e]
__global__ __launch_bounds__(256) void theta_combine_kernel(
    const float* __restrict__ part, unsigned short* __restrict__ th0,
    unsigned short* __restrict__ th1, unsigned short* __restrict__ th2) {
  const size_t i = (size_t)blockIdx.x * 256 + threadIdx.x;  // float4 index
  float4 s = ((const float4*)part)[i];
#pragma unroll
  for (int z = 1; z < KSPLIT; ++z) {
    const float4 v = ((const float4*)(part + (size_t)z * D * D))[i];
    s.x += v.x; s.y += v.y; s.z += v.z; s.w += v.w;
  }
  const float vv[4] = {-s.x, -s.y, -s.z, -s.w};
  ushort4 h0, h1, h2;
  unsigned short* p0[4] = {&h0.x, &h0.y, &h0.z, &h0.w};
  unsigned short* p1[4] = {&h1.x, &h1.y, &h1.z, &h1.w};
  unsigned short* p2[4] = {&h2.x, &h2.y, &h2.z, &h2.w};
#pragma unroll
  for (int c = 0; c < 4; ++c) {
    const float v = vv[c];
    const unsigned short a0 = f2bf(v);
    const float r1 = v - bf2f(a0);
    const unsigned short a1 = f2bf(r1);
    const float r2 = r1 - bf2f(a1);
    *p0[c] = a0; *p1[c] = a1; *p2[c] = f2bf(r2);
  }
  ((ushort4*)th0)[i] = h0;
  ((ushort4*)th1)[i] = h1;
  ((ushort4*)th2)[i] = h2;
}

__global__ __launch_bounds__(256) void bias_kernel(const float* __restrict__ ps,
                                                   float* __restrict__ bias) {
  __shared__ float part[4][64];
  const int dc = threadIdx.x & 63;
  const int sl = threadIdx.x >> 6;
  const int d  = blockIdx.x * 64 + dc;
  float s = 0.f;
  for (int k = sl * 256; k < sl * 256 + 256; ++k) s += ps[(size_t)k * D + d];
  part[sl][dc] = s;
  __syncthreads();
  if (threadIdx.x < 64) {
    const int c = threadIdx.x;
    bias[blockIdx.x * 64 + c] =
        -(part[0][c] + part[1][c] + part[2][c] + part[3][c]);
  }
}

// out0 = inp; y* = split3(relu(inp)) in [m][e] bf16.
__global__ __launch_bounds__(256) void init_kernel(
    const float* __restrict__ inp, float* __restrict__ out0,
    unsigned short* __restrict__ y0, unsigned short* __restrict__ y1,
    unsigned short* __restrict__ y2) {
  const size_t i = (size_t)blockIdx.x * 256 + threadIdx.x;  // float4 index
  const float4 v = ((const float4*)inp)[i];
  ((float4*)out0)[i] = v;
  const float vv[4] = {fmaxf(v.x, 0.f), fmaxf(v.y, 0.f),
                       fmaxf(v.z, 0.f), fmaxf(v.w, 0.f)};
  ushort4 h0, h1, h2;
  unsigned short* p0[4] = {&h0.x, &h0.y, &h0.z, &h0.w};
  unsigned short* p1[4] = {&h1.x, &h1.y, &h1.z, &h1.w};
  unsigned short* p2[4] = {&h2.x, &h2.y, &h2.z, &h2.w};
#pragma unroll
  for (int c = 0; c < 4; ++c) {
    const unsigned short a0 = f2bf(vv[c]);
    const float r1 = vv[c] - bf2f(a0);
    const unsigned short a1 = f2bf(r1);
    const float r2 = r1 - bf2f(a1);
    *p0[c] = a0; *p1[c] = a1; *p2[c] = f2bf(r2);
  }
  ((ushort4*)y0)[i] = h0;
  ((ushort4*)y1)[i] = h1;
  ((ushort4*)y2)[i] = h2;
}

// ---------------------------------------------------------------------------
// feval<MODE>: k[m][n] = bias[n] + sum_e A[m][e]*theta[n][e], A = split yin.
//  MODE 0: acc = k;   y = u + dt/2 k     MODE 1: acc += 2k;  y = u + dt/2 k
//  MODE 2: acc += 2k; y = u + dt   k     MODE 3: y = u + dt/6 (acc+k) -> out
// All modes: yw* = split3(relu(y)).
// 64x64 tile, 128 thr (2 waves, each 32m x 64n = 2x4 subtiles of 16x16x32).
// Per slab: 12 DMA + 18 ds_read_b128 + 48 MFMA per wave; double-buffered.
// ---------------------------------------------------------------------------
template <int MODE>
__global__ __launch_bounds__(128) void feval_kernel(
    const unsigned short* __restrict__ ya0, const unsigned short* __restrict__ ya1,
    const unsigned short* __restrict__ ya2, const unsigned short* __restrict__ th0,
    const unsigned short* __restrict__ th1, const unsigned short* __restrict__ th2,
    const float* __restrict__ bias, const float* __restrict__ bt, int step,
    const float* __restrict__ uStd, float* __restrict__ acc,
    unsigned short* __restrict__ yw0, unsigned short* __restrict__ yw1,
    unsigned short* __restrict__ yw2, float* __restrict__ outStd) {
  __shared__ unsigned short Ab[2][3][64][32];  // [buf][split][m][k] 24 KB
  __shared__ unsigned short Bb[2][3][64][32];  // [buf][split][n][k] 24 KB
  const int t    = threadIdx.x;
  const int w    = t >> 6;
  const int lane = t & 63;
  const int m0   = blockIdx.x * 64;
  const int n0   = blockIdx.y * 64;
  const float dt = bt[step + 1] - bt[step];
  const unsigned short* Aarr[3] = {ya0, ya1, ya2};
  const unsigned short* Tarr[3] = {th0, th1, th2};

  auto dma = [&](int buf, int slab) {
    const int e0 = slab * 32;
#pragma unroll
    for (int s = 0; s < 3; ++s) {
#pragma unroll
      for (int h = 0; h < 2; ++h) {
        const int lin = s * 256 + h * 128 + t;   // 0..767, split-uniform
        const int r   = (lin >> 2) & 63;         // row in tile
        const int q   = lin & 3;                 // 16B quad in 64B row
        // LDS linear offset lin*16B == Ab[buf][s][r][q*8] by construction.
        unsigned short* lA = &Ab[buf][0][0][0] + (size_t)(s * 256 + h * 128 + w * 64) * 8;
        unsigned short* lB = &Bb[buf][0][0][0] + (size_t)(s * 256 + h * 128 + w * 64) * 8;
        glds16(Aarr[s] + (size_t)(m0 + r) * D + e0 + q * 8, lA);
        glds16(Tarr[s] + (size_t)(n0 + r) * D + e0 + q * 8, lB);
      }
    }
  };

  f32x4 C[2][4];
#pragma unroll
  for (int ms = 0; ms < 2; ++ms)
#pragma unroll
    for (int ns = 0; ns < 4; ++ns) C[ms][ns] = (f32x4){0.f, 0.f, 0.f, 0.f};

  dma(0, 0);
  __syncthreads();

  const int nl = lane & 15;
  const int q8 = (lane >> 4) * 8;
  for (int slab = 0; slab < 16; ++slab) {
    const int buf = slab & 1;
    if (slab + 1 < 16) dma(buf ^ 1, slab + 1);
    short8 av[2][3], bv[4][3];
#pragma unroll
    for (int ms = 0; ms < 2; ++ms)
#pragma unroll
      for (int s = 0; s < 3; ++s)
        av[ms][s] = *(const short8*)&Ab[buf][s][w * 32 + ms * 16 + nl][q8];
#pragma unroll
    for (int ns = 0; ns < 4; ++ns)
#pragma unroll
      for (int s = 0; s < 3; ++s)
        bv[ns][s] = *(const short8*)&Bb[buf][s][ns * 16 + nl][q8];
#pragma unroll
    for (int ms = 0; ms < 2; ++ms)
#pragma unroll
      for (int ns = 0; ns < 4; ++ns) {
        f32x4 c = C[ms][ns];
        c = __builtin_amdgcn_mfma_f32_16x16x32_bf16(av[ms][0], bv[ns][0], c, 0, 0, 0);
        c = __builtin_amdgcn_mfma_f32_16x16x32_bf16(av[ms][0], bv[ns][1], c, 0, 0, 0);
        c = __builtin_amdgcn_mfma_f32_16x16x32_bf16(av[ms][1], bv[ns][0], c, 0, 0, 0);
        c = __builtin_amdgcn_mfma_f32_16x16x32_bf16(av[ms][0], bv[ns][2], c, 0, 0, 0);
        c = __builtin_amdgcn_mfma_f32_16x16x32_bf16(av[ms][1], bv[ns][1], c, 0, 0, 0);
        c = __builtin_amdgcn_mfma_f32_16x16x32_bf16(av[ms][2], bv[ns][0], c, 0, 0, 0);
        C[ms][ns] = c;
      }
    __syncthreads();
  }

  // ---- epilogue: C/D layout col(n)=lane&15, row(m)=(lane>>4)*4+reg ---------
  const float cn = (MODE == 2) ? dt : 0.5f * dt;
  const float s6 = dt * (1.f / 6.f);
  const int qr = (lane >> 4) * 4;
#pragma unroll
  for (int ms = 0; ms < 2; ++ms) {
#pragma unroll
    for (int ns = 0; ns < 4; ++ns) {
      const int n = n0 + ns * 16 + nl;
      const float bb = bias[n];
#pragma unroll
      for (int r = 0; r < 4; ++r) {
        const int m = m0 + w * 32 + ms * 16 + qr + r;
        const size_t off = (size_t)m * D + n;
        const float kv = C[ms][ns][r] + bb;
        float y;
        if constexpr (MODE == 0) {
          acc[off] = kv;
          y = fmaf(cn, kv, uStd[off]);
        } else if constexpr (MODE <= 2) {
          const float a = acc[off];
          acc[off] = fmaf(2.f, kv, a);
          y = fmaf(cn, kv, uStd[off]);
        } else {
          const float a = acc[off];
          y = fmaf(s6, a + kv, uStd[off]);
          outStd[off] = y;
        }
        const float ry = fmaxf(y, 0.f);
        const unsigned short h0 = f2bf(ry);
        const float r1 = ry - bf2f(h0);
        const unsigned short h1 = f2bf(r1);
        const float r2 = r1 - bf2f(h1);
        yw0[off] = h0;
        yw1[off] = h1;
        yw2[off] = f2bf(r2);
      }
    }
  }
}

}  // namespace

extern "C" void kernel_launch(void* const* d_in, const int* in_sizes, int n_in,
                              void* d_out, int out_size, void* d_ws, size_t ws_size,
                              hipStream_t stream) {
  (void)in_sizes; (void)n_in; (void)out_size; (void)ws_size;
  const float* xs  = (const float*)d_in[0];  // x_params (K,1,D)
  const float* ps  = (const float*)d_in[1];  // p_params (K,1,D)
  // d_in[2] Mbar, d_in[3] Mbar_b: identity -> inv() no-op
  const float* inp = (const float*)d_in[4];  // (M,1,D)
  const float* bt  = (const float*)d_in[5];  // (T,)
  float* out = (float*)d_out;                // (T, M, 1, D)
  float* ws  = (float*)d_ws;

  float* acc  = ws;                          // M*D floats (8 MB)
  float* bias = acc + (size_t)M * D;         // 512
  unsigned short* th0 = (unsigned short*)(bias + 512);   // D*D bf16 each
  unsigned short* th1 = th0 + (size_t)D * D;
  unsigned short* th2 = th1 + (size_t)D * D;
  unsigned short* ya0 = th2 + (size_t)D * D;             // M*D bf16 each
  unsigned short* ya1 = ya0 + (size_t)M * D;
  unsigned short* ya2 = ya1 + (size_t)M * D;
  unsigned short* yb0 = ya2 + (size_t)M * D;
  unsigned short* yb1 = yb0 + (size_t)M * D;
  unsigned short* yb2 = yb1 + (size_t)M * D;             // total ~34 MB
  float* part = acc;  // theta partials: KSPLIT*D*D = M*D floats exactly

  theta_partial_kernel<<<dim3(8, 8, KSPLIT), 256, 0, stream>>>(xs, ps, part);
  theta_combine_kernel<<<(D * D) / (4 * 256), 256, 0, stream>>>(part, th0, th1, th2);
  bias_kernel<<<D / 64, 256, 0, stream>>>(ps, bias);
  init_kernel<<<(M * D) / (4 * 256), 256, 0, stream>>>(inp, out, ya0, ya1, ya2);

  const dim3 grid(M / 64, D / 64);  // (64, 8) = 512 blocks
  for (int s = 0; s < 5; ++s) {
    float* u     = out + (size_t)s * M * D;
    float* unext = out + (size_t)(s + 1) * M * D;
    feval_kernel<0><<<grid, 128, 0, stream>>>(ya0, ya1, ya2, th0, th1, th2, bias,
                                              bt, s, u, acc, yb0, yb1, yb2, nullptr);
    feval_kernel<1><<<grid, 128, 0, stream>>>(yb0, yb1, yb2, th0, th1, th2, bias,
                                              bt, s, u, acc, ya0, ya1, ya2, nullptr);
    feval_kernel<2><<<grid, 128, 0, stream>>>(ya0, ya1, ya2, th0, th1, th2, bias,
                                              bt, s, u, acc, yb0, yb1, yb2, nullptr);
    feval_kernel<3><<<grid, 128, 0, stream>>>(yb0, yb1, yb2, th0, th1, th2, bias,
                                              bt, s, u, acc, ya0, ya1, ya2, unext);
  }
}

// Round 6
// 590.409 us; speedup vs baseline: 2.2461x; 1.3191x over previous
//
#include <hip/hip_runtime.h>

// ShootingBlock: only the u-trajectory is observable (traj records y[2K:];
// du = relu(u)@theta^T + bias is self-contained; Mbar/Mbar_b are identity).
//
// R6 (from R5's 35us/feval): two fixes.
//  1. R5's fragment reads were 8-way bank-conflicted (rows at 64B stride ->
//     2 bank-groups). global_load_lds pins LDS dest = base + lane*16, so we
//     swizzle the GLOBAL side: row r's quad q lands in LDS slot q^(r&3);
//     reads use slot = qq^(r&3) -> 8 bank-groups x 2-way (free).
//  2. 256-thr blocks (4 waves of 32x32 subtiles), grid (64,8)=512 ->
//     2 blocks/CU = 2 waves/SIMD so LDS/MFMA/DMA pipes overlap.
// Numerics unchanged: split-3 bf16, 6 MFMA products, fp32 accumulate.

namespace {

constexpr int KP = 1024;
constexpr int D  = 512;
constexpr int M  = 4096;

typedef __attribute__((ext_vector_type(8))) short short8;   // 8 bf16 (4 VGPRs)
typedef __attribute__((ext_vector_type(4))) float f32x4;

__device__ __forceinline__ unsigned short f2bf(float f) {  // RNE
  unsigned int u = __float_as_uint(f);
  u += 0x7FFF + ((u >> 16) & 1);
  return (unsigned short)(u >> 16);
}
__device__ __forceinline__ float bf2f(unsigned short h) {
  return __uint_as_float(((unsigned int)h) << 16);
}

__device__ __forceinline__ void glds16(const unsigned short* g, unsigned short* l) {
  __builtin_amdgcn_global_load_lds(
      (__attribute__((address_space(1))) const void*)g,
      (__attribute__((address_space(3))) void*)l, 16, 0, 0);
}

// ---------------------------------------------------------------------------
// part[z][d][e] = sum_{k in chunk z} ps[k][d] * relu(xs[k][e])   (std layout)
// ---------------------------------------------------------------------------
constexpr int KSPLIT = 8;

__global__ __launch_bounds__(256) void theta_partial_kernel(
    const float* __restrict__ xs, const float* __restrict__ ps,
    float* __restrict__ part) {
  __shared__ float As[32][68];  // ps, d-block
  __shared__ float Bs[32][68];  // relu(xs), e-block
  const int d0 = blockIdx.x * 64;
  const int e0 = blockIdx.y * 64;
  const int kb = blockIdx.z * (KP / KSPLIT);
  const int t  = threadIdx.x;
  const int tx = t & 15, ty = t >> 4;
  float acc[4][4] = {};

  for (int k0 = kb; k0 < kb + KP / KSPLIT; k0 += 32) {
#pragma unroll
    for (int p = 0; p < 2; ++p) {
      const int idx = t + p * 256;
      const int c4  = idx & 15;
      const int row = idx >> 4;
      const float4 av = *(const float4*)(ps + (size_t)(k0 + row) * D + d0 + c4 * 4);
      *(float4*)&As[row][c4 * 4] = av;
      float4 bv = *(const float4*)(xs + (size_t)(k0 + row) * D + e0 + c4 * 4);
      bv.x = fmaxf(bv.x, 0.f); bv.y = fmaxf(bv.y, 0.f);
      bv.z = fmaxf(bv.z, 0.f); bv.w = fmaxf(bv.w, 0.f);
      *(float4*)&Bs[row][c4 * 4] = bv;
    }
    __syncthreads();
#pragma unroll
    for (int kk = 0; kk < 32; ++kk) {
      const float4 a4 = *(const float4*)&As[kk][ty * 4];
      const float4 b4 = *(const float4*)&Bs[kk][tx * 4];
      const float a[4] = {a4.x, a4.y, a4.z, a4.w};
      const float b[4] = {b4.x, b4.y, b4.z, b4.w};
#pragma unroll
      for (int i = 0; i < 4; ++i)
#pragma unroll
        for (int j = 0; j < 4; ++j)
          acc[i][j] = fmaf(a[i], b[j], acc[i][j]);
    }
    __syncthreads();
  }
  float* dst = part + (size_t)blockIdx.z * D * D;
#pragma unroll
  for (int i = 0; i < 4; ++i) {
    float4 v;
    v.x = acc[i][0]; v.y = acc[i][1]; v.z = acc[i][2]; v.w = acc[i][3];
    *(float4*)(dst + (size_t)(d0 + ty * 4 + i) * D + e0 + tx * 4) = v;
  }
}

// theta = -(sum partials); split-3 into bf16 arrays th0,th1,th2 [d][e]
__global__ __launch_bounds__(256) void theta_combine_kernel(
    const float* __restrict__ part, unsigned short* __restrict__ th0,
    unsigned short* __restrict__ th1, unsigned short* __restrict__ th2) {
  const size_t i = (size_t)blockIdx.x * 256 + threadIdx.x;  // float4 index
  float4 s = ((const float4*)part)[i];
#pragma unroll
  for (int z = 1; z < KSPLIT; ++z) {
    const float4 v = ((const float4*)(part + (size_t)z * D * D))[i];
    s.x += v.x; s.y += v.y; s.z += v.z; s.w += v.w;
  }
  const float vv[4] = {-s.x, -s.y, -s.z, -s.w};
  ushort4 h0, h1, h2;
  unsigned short* p0[4] = {&h0.x, &h0.y, &h0.z, &h0.w};
  unsigned short* p1[4] = {&h1.x, &h1.y, &h1.z, &h1.w};
  unsigned short* p2[4] = {&h2.x, &h2.y, &h2.z, &h2.w};
#pragma unroll
  for (int c = 0; c < 4; ++c) {
    const float v = vv[c];
    const unsigned short a0 = f2bf(v);
    const float r1 = v - bf2f(a0);
    const unsigned short a1 = f2bf(r1);
    const float r2 = r1 - bf2f(a1);
    *p0[c] = a0; *p1[c] = a1; *p2[c] = f2bf(r2);
  }
  ((ushort4*)th0)[i] = h0;
  ((ushort4*)th1)[i] = h1;
  ((ushort4*)th2)[i] = h2;
}

__global__ __launch_bounds__(256) void bias_kernel(const float* __restrict__ ps,
                                                   float* __restrict__ bias) {
  __shared__ float part[4][64];
  const int dc = threadIdx.x & 63;
  const int sl = threadIdx.x >> 6;
  const int d  = blockIdx.x * 64 + dc;
  float s = 0.f;
  for (int k = sl * 256; k < sl * 256 + 256; ++k) s += ps[(size_t)k * D + d];
  part[sl][dc] = s;
  __syncthreads();
  if (threadIdx.x < 64) {
    const int c = threadIdx.x;
    bias[blockIdx.x * 64 + c] =
        -(part[0][c] + part[1][c] + part[2][c] + part[3][c]);
  }
}

// out0 = inp; y* = split3(relu(inp)) in [m][e] bf16.
__global__ __launch_bounds__(256) void init_kernel(
    const float* __restrict__ inp, float* __restrict__ out0,
    unsigned short* __restrict__ y0, unsigned short* __restrict__ y1,
    unsigned short* __restrict__ y2) {
  const size_t i = (size_t)blockIdx.x * 256 + threadIdx.x;  // float4 index
  const float4 v = ((const float4*)inp)[i];
  ((float4*)out0)[i] = v;
  const float vv[4] = {fmaxf(v.x, 0.f), fmaxf(v.y, 0.f),
                       fmaxf(v.z, 0.f), fmaxf(v.w, 0.f)};
  ushort4 h0, h1, h2;
  unsigned short* p0[4] = {&h0.x, &h0.y, &h0.z, &h0.w};
  unsigned short* p1[4] = {&h1.x, &h1.y, &h1.z, &h1.w};
  unsigned short* p2[4] = {&h2.x, &h2.y, &h2.z, &h2.w};
#pragma unroll
  for (int c = 0; c < 4; ++c) {
    const unsigned short a0 = f2bf(vv[c]);
    const float r1 = vv[c] - bf2f(a0);
    const unsigned short a1 = f2bf(r1);
    const float r2 = r1 - bf2f(a1);
    *p0[c] = a0; *p1[c] = a1; *p2[c] = f2bf(r2);
  }
  ((ushort4*)y0)[i] = h0;
  ((ushort4*)y1)[i] = h1;
  ((ushort4*)y2)[i] = h2;
}

// ---------------------------------------------------------------------------
// feval<MODE>: k[m][n] = bias[n] + sum_e A[m][e]*theta[n][e], A = split yin.
//  MODE 0: acc = k;   y = u + dt/2 k     MODE 1: acc += 2k;  y = u + dt/2 k
//  MODE 2: acc += 2k; y = u + dt   k     MODE 3: y = u + dt/6 (acc+k) -> out
// All modes: yw* = split3(relu(y)).
// 64x64 tile, 256 thr = 4 waves, wave w -> 32x32 subtile (msb=(w&1)*32,
// nsb=(w>>1)*32), 2x2 C-frags of 16x16x32. LDS: [buf][A/B][s][row][32k],
// quad slot XOR-swizzled (slot = q ^ (row&3)) so fragment b128 reads are
// conflict-free. Staging: 6 glds16/wave/slab, double-buffered.
// ---------------------------------------------------------------------------
template <int MODE>
__global__ __launch_bounds__(256) void feval_kernel(
    const unsigned short* __restrict__ ya0, const unsigned short* __restrict__ ya1,
    const unsigned short* __restrict__ ya2, const unsigned short* __restrict__ th0,
    const unsigned short* __restrict__ th1, const unsigned short* __restrict__ th2,
    const float* __restrict__ bias, const float* __restrict__ bt, int step,
    const float* __restrict__ uStd, float* __restrict__ acc,
    unsigned short* __restrict__ yw0, unsigned short* __restrict__ yw1,
    unsigned short* __restrict__ yw2, float* __restrict__ outStd) {
  __shared__ unsigned short lds[2][2][3][64][32];  // 48 KB
  const int t    = threadIdx.x;
  const int w    = t >> 6;
  const int lane = t & 63;
  const int nl   = lane & 15;
  const int qq   = lane >> 4;        // quad 0..3 (16B groups of a 64B row)
  const int m0   = blockIdx.x * 64;
  const int n0   = blockIdx.y * 64;
  const int msb  = (w & 1) * 32;
  const int nsb  = (w >> 1) * 32;
  const float dt = bt[step + 1] - bt[step];
  const unsigned short* Aarr[3] = {ya0, ya1, ya2};
  const unsigned short* Tarr[3] = {th0, th1, th2};

  // chunk c (16B units) covers (split s = c>>8, row r = (c&255)>>2, slot qs =
  // c&3); that slot holds global quad q = qs ^ (r&3).
  auto dma = [&](int buf, int slab) {
    const int e0 = slab * 32;
#pragma unroll
    for (int j = 0; j < 3; ++j) {
      const int cb  = (w * 3 + j) * 64;       // wave-uniform chunk base
      const int s   = cb >> 8;                // wave-uniform split
      const int rem = (cb & 255) + lane;      // stays < 256 (cb % 64 == 0)
      const int r   = rem >> 2;
      const int q   = (rem & 3) ^ (r & 3);
      unsigned short* dA = &lds[buf][0][0][0][0] + (size_t)cb * 8;
      unsigned short* dB = &lds[buf][1][0][0][0] + (size_t)cb * 8;
      glds16(Aarr[s] + (size_t)(m0 + r) * D + e0 + q * 8, dA);
      glds16(Tarr[s] + (size_t)(n0 + r) * D + e0 + q * 8, dB);
    }
  };

  f32x4 C[2][2];
#pragma unroll
  for (int ms = 0; ms < 2; ++ms)
#pragma unroll
    for (int ns = 0; ns < 2; ++ns) C[ms][ns] = (f32x4){0.f, 0.f, 0.f, 0.f};

  dma(0, 0);
  __syncthreads();

  for (int slab = 0; slab < 16; ++slab) {
    const int buf = slab & 1;
    if (slab + 1 < 16) dma(buf ^ 1, slab + 1);
    short8 av[2][3], bv[2][3];
#pragma unroll
    for (int ms = 0; ms < 2; ++ms) {
      const int r   = msb + ms * 16 + nl;
      const int pos = (qq ^ (r & 3)) * 8;
#pragma unroll
      for (int s = 0; s < 3; ++s)
        av[ms][s] = *(const short8*)&lds[buf][0][s][r][pos];
    }
#pragma unroll
    for (int ns = 0; ns < 2; ++ns) {
      const int r   = nsb + ns * 16 + nl;
      const int pos = (qq ^ (r & 3)) * 8;
#pragma unroll
      for (int s = 0; s < 3; ++s)
        bv[ns][s] = *(const short8*)&lds[buf][1][s][r][pos];
    }
#pragma unroll
    for (int ms = 0; ms < 2; ++ms)
#pragma unroll
      for (int ns = 0; ns < 2; ++ns) {
        f32x4 c = C[ms][ns];
        c = __builtin_amdgcn_mfma_f32_16x16x32_bf16(av[ms][0], bv[ns][0], c, 0, 0, 0);
        c = __builtin_amdgcn_mfma_f32_16x16x32_bf16(av[ms][0], bv[ns][1], c, 0, 0, 0);
        c = __builtin_amdgcn_mfma_f32_16x16x32_bf16(av[ms][1], bv[ns][0], c, 0, 0, 0);
        c = __builtin_amdgcn_mfma_f32_16x16x32_bf16(av[ms][0], bv[ns][2], c, 0, 0, 0);
        c = __builtin_amdgcn_mfma_f32_16x16x32_bf16(av[ms][1], bv[ns][1], c, 0, 0, 0);
        c = __builtin_amdgcn_mfma_f32_16x16x32_bf16(av[ms][2], bv[ns][0], c, 0, 0, 0);
        C[ms][ns] = c;
      }
    __syncthreads();
  }

  // ---- epilogue: C/D layout col(n)=lane&15, row(m)=(lane>>4)*4+reg ---------
  const float cn = (MODE == 2) ? dt : 0.5f * dt;
  const float s6 = dt * (1.f / 6.f);
#pragma unroll
  for (int ms = 0; ms < 2; ++ms) {
#pragma unroll
    for (int ns = 0; ns < 2; ++ns) {
      const int n = n0 + nsb + ns * 16 + nl;
      const float bb = bias[n];
#pragma unroll
      for (int r = 0; r < 4; ++r) {
        const int m = m0 + msb + ms * 16 + qq * 4 + r;
        const size_t off = (size_t)m * D + n;
        const float kv = C[ms][ns][r] + bb;
        float y;
        if constexpr (MODE == 0) {
          acc[off] = kv;
          y = fmaf(cn, kv, uStd[off]);
        } else if constexpr (MODE <= 2) {
          const float a = acc[off];
          acc[off] = fmaf(2.f, kv, a);
          y = fmaf(cn, kv, uStd[off]);
        } else {
          const float a = acc[off];
          y = fmaf(s6, a + kv, uStd[off]);
          outStd[off] = y;
        }
        const float ry = fmaxf(y, 0.f);
        const unsigned short h0 = f2bf(ry);
        const float r1 = ry - bf2f(h0);
        const unsigned short h1 = f2bf(r1);
        const float r2 = r1 - bf2f(h1);
        yw0[off] = h0;
        yw1[off] = h1;
        yw2[off] = f2bf(r2);
      }
    }
  }
}

}  // namespace

extern "C" void kernel_launch(void* const* d_in, const int* in_sizes, int n_in,
                              void* d_out, int out_size, void* d_ws, size_t ws_size,
                              hipStream_t stream) {
  (void)in_sizes; (void)n_in; (void)out_size; (void)ws_size;
  const float* xs  = (const float*)d_in[0];  // x_params (K,1,D)
  const float* ps  = (const float*)d_in[1];  // p_params (K,1,D)
  // d_in[2] Mbar, d_in[3] Mbar_b: identity -> inv() no-op
  const float* inp = (const float*)d_in[4];  // (M,1,D)
  const float* bt  = (const float*)d_in[5];  // (T,)
  float* out = (float*)d_out;                // (T, M, 1, D)
  float* ws  = (float*)d_ws;

  float* acc  = ws;                          // M*D floats (8 MB)
  float* bias = acc + (size_t)M * D;         // 512
  unsigned short* th0 = (unsigned short*)(bias + 512);   // D*D bf16 each
  unsigned short* th1 = th0 + (size_t)D * D;
  unsigned short* th2 = th1 + (size_t)D * D;
  unsigned short* ya0 = th2 + (size_t)D * D;             // M*D bf16 each
  unsigned short* ya1 = ya0 + (size_t)M * D;
  unsigned short* ya2 = ya1 + (size_t)M * D;
  unsigned short* yb0 = ya2 + (size_t)M * D;
  unsigned short* yb1 = yb0 + (size_t)M * D;
  unsigned short* yb2 = yb1 + (size_t)M * D;             // total ~34 MB
  float* part = acc;  // theta partials: KSPLIT*D*D = M*D floats exactly

  theta_partial_kernel<<<dim3(8, 8, KSPLIT), 256, 0, stream>>>(xs, ps, part);
  theta_combine_kernel<<<(D * D) / (4 * 256), 256, 0, stream>>>(part, th0, th1, th2);
  bias_kernel<<<D / 64, 256, 0, stream>>>(ps, bias);
  init_kernel<<<(M * D) / (4 * 256), 256, 0, stream>>>(inp, out, ya0, ya1, ya2);

  const dim3 grid(M / 64, D / 64);  // (64, 8) = 512 blocks, 2/CU, 2 waves/SIMD
  for (int s = 0; s < 5; ++s) {
    float* u     = out + (size_t)s * M * D;
    float* unext = out + (size_t)(s + 1) * M * D;
    feval_kernel<0><<<grid, 256, 0, stream>>>(ya0, ya1, ya2, th0, th1, th2, bias,
                                              bt, s, u, acc, yb0, yb1, yb2, nullptr);
    feval_kernel<1><<<grid, 256, 0, stream>>>(yb0, yb1, yb2, th0, th1, th2, bias,
                                              bt, s, u, acc, ya0, ya1, ya2, nullptr);
    feval_kernel<2><<<grid, 256, 0, stream>>>(ya0, ya1, ya2, th0, th1, th2, bias,
                                              bt, s, u, acc, yb0, yb1, yb2, nullptr);
    feval_kernel<3><<<grid, 256, 0, stream>>>(yb0, yb1, yb2, th0, th1, th2, bias,
                                              bt, s, u, acc, ya0, ya1, ya2, unext);
  }
}